// Round 14
// baseline (62.965 us; speedup 1.0000x reference)
//
#include <hip/hip_runtime.h>

// out[b,s,:] = W[:, text[b,s]] + bias + pe[s,:]
// text: int32 [B,S]; W: f32 [D, VOCAB]; bias: f32 [D]; pe: f32 [MAX_LEN, D]
//
// Round 14: SINGLE KERNEL = r12's gather with an in-kernel token scan.
// Per block (one 64-vocab x 64-d tile):
//   1. issue 16 coalesced W float4 loads (stay in flight)
//   2. scan all 8192 text entries (L1/L2-resident 32KB, 32 coalesced loads)
//      appending matches to an LDS list via LDS-atomic cursor  [hidden under 1]
//   3. write W regs -> transposed LDS tile
//   4. sync; process list exactly like r12: 16 tokens in independent flight
//      per wave-quad, ds_read_b128 + float4 pe load + float4 out store.
// Removes bin_k (~3.5us serial on 1 CU) + dispatch gap. No workspace.
// r10 lesson: no nontemporal. r11: no dispatch chains. r13: no serialized
// ballot-match loop — list first, then parallel processing.

#define VOCAB  32000
#define DMODEL 1024
#define S_LEN  2048
#define B_N    4
#define NTOK   (B_N * S_LEN)     // 8192
#define VT     64                // vocab entries per tile
#define DT     64                // d rows per tile
#define NBIN   (VOCAB / VT)      // 500
#define NDT    (DMODEL / DT)     // 16
#define NBLK   (NBIN * NDT)      // 8000
#define LROW   (DT + 4)          // 68 floats = 272B rows (16B-aligned)
#define LCAP   256               // list capacity (mean 16.4, P(>256) ~ 0)

__global__ __launch_bounds__(256, 8) void embed_k(const int* __restrict__ text,
                                                  const float* __restrict__ W,
                                                  const float* __restrict__ bias,
                                                  const float* __restrict__ pe,
                                                  float* __restrict__ out) {
    __shared__ float lds[VT][LROW];          // 17.4 KB
    __shared__ int   list[LCAP];             // packed (tokl<<13)|bs
    __shared__ int   cnt;

    const int bid = blockIdx.x;
    const int vt = bid >> 4;                 // 0..499
    const int dt = bid & (NDT - 1);          // 0..15
    const int v0 = vt * VT;
    const int d0 = dt * DT;
    const int t  = threadIdx.x;

    if (t == 0) cnt = 0;
    __syncthreads();

    // ---- 1. issue W[d0:d0+64][v0:v0+64] loads (16B coalesced, in flight) ----
    const int c4 = t & 15;                   // float4 column (v) 0..15
    const int r0 = t >> 4;                   // row (d) 0..15
    float4 w[4];
    #pragma unroll
    for (int i = 0; i < 4; ++i)
        w[i] = *reinterpret_cast<const float4*>(
            W + (size_t)(d0 + r0 + i * 16) * VOCAB + v0 + c4 * 4);

    // ---- 2. scan text -> LDS list (hides under the W loads) ----
    #pragma unroll 8
    for (int i = 0; i < NTOK / 256; ++i) {   // 32 coalesced 1KB block-loads
        const int idx = i * 256 + t;
        const int tok = text[idx];
        const unsigned tl = (unsigned)(tok - v0);
        if (tl < (unsigned)VT) {
            const int p = atomicAdd(&cnt, 1);
            list[p] = (int)((tl << 13) | (unsigned)idx);
        }
    }

    // ---- 3. W regs -> transposed LDS [v][d] ----
    #pragma unroll
    for (int i = 0; i < 4; ++i) {
        const int row = r0 + i * 16;
        lds[c4 * 4 + 0][row] = w[i].x;
        lds[c4 * 4 + 1][row] = w[i].y;
        lds[c4 * 4 + 2][row] = w[i].z;
        lds[c4 * 4 + 3][row] = w[i].w;
    }
    __syncthreads();

    // ---- 4. process list: r12-exact parallel pipelined epilogue ----
    const int n    = cnt;
    const int lane = t & 63;
    const int wv   = t >> 6;                 // wave 0..3
    const int grp  = lane >> 4;              // token group 0..3 within wave
    const int ld   = lane & 15;              // d-float4 index 0..15
    const int d    = d0 + ld * 4;
    const float4 b4 = *reinterpret_cast<const float4*>(bias + d);

    for (int i = wv * 4 + grp; i < n; i += 16) {
        const int e    = list[i];
        const int tokl = e >> 13;
        const int bs   = e & (NTOK - 1);
        const int s    = bs & (S_LEN - 1);
        const float4 w4 = *reinterpret_cast<const float4*>(&lds[tokl][ld * 4]);
        const float4 p4 = *reinterpret_cast<const float4*>(pe + (size_t)s * DMODEL + d);
        float4 o;
        o.x = w4.x + b4.x + p4.x;
        o.y = w4.y + b4.y + p4.y;
        o.z = w4.z + b4.z + p4.z;
        o.w = w4.w + b4.w + p4.w;
        *reinterpret_cast<float4*>(out + (size_t)bs * DMODEL + d) = o;
    }
}

extern "C" void kernel_launch(void* const* d_in, const int* in_sizes, int n_in,
                              void* d_out, int out_size, void* d_ws, size_t ws_size,
                              hipStream_t stream) {
    const int*   text = (const int*)d_in[0];
    const float* W    = (const float*)d_in[1];
    const float* bias = (const float*)d_in[2];
    const float* pe   = (const float*)d_in[3];
    float*       out  = (float*)d_out;

    embed_k<<<NBLK, 256, 0, stream>>>(text, W, bias, pe, out);
}

// Round 15
// 38.917 us; speedup vs baseline: 1.6179x; 1.6179x over previous
//
#include <hip/hip_runtime.h>

// out[b,s,:] = W[:, text[b,s]] + bias + pe[s,:]
// text: int32 [B,S]; W: f32 [D, VOCAB]; bias: f32 [D]; pe: f32 [MAX_LEN, D]
//
// Round 15 = r12 restored (best: 39.1us). Fused 1-block bin (hist + wave-shfl
// scan + scatter) + 8000-block coalesced W-sweep gather with transposed-LDS
// tile and float4 epilogue.
// Proven-dead alternatives: nontemporal hints (r10, L3 bypass +16us),
// multi-dispatch binning (r11, launch gaps +12us), in-kernel ballot scan
// (r13, +17us), in-kernel list scan (r14, +24us), in-block pipelined
// multi-tile blocks (r6, +5us), 512B-chunk/transposed stage (r8, +1us).

#define VOCAB  32000
#define DMODEL 1024
#define S_LEN  2048
#define B_N    4
#define NTOK   (B_N * S_LEN)     // 8192
#define VT     64                // vocab entries per tile
#define DT     64                // d rows per tile
#define NBIN   (VOCAB / VT)      // 500
#define NDT    (DMODEL / DT)     // 16
#define NBLK   (NBIN * NDT)      // 8000
#define LROW   (DT + 4)          // 68 floats = 272 B rows (16B-aligned)

// ---- pass 1: fused bin (hist + wave-scan + scatter), single block ----
__global__ __launch_bounds__(1024) void bin_k(const int* __restrict__ text,
                                              int2* __restrict__ sorted,
                                              int* __restrict__ tile_off) {
    __shared__ int cnt[512];
    __shared__ int cur[512];
    const int t = threadIdx.x;
    if (t < 512) cnt[t] = 0;
    __syncthreads();

    int toks[8];
    #pragma unroll
    for (int j = 0; j < 8; ++j) {
        toks[j] = text[t * 8 + j];
        atomicAdd(&cnt[toks[j] >> 6], 1);
    }
    __syncthreads();

    // exclusive scan over 512 bins by wave 0: 8 bins/lane + shfl wave-scan
    if (t < 64) {
        const int base = t * 8;
        int loc[8];
        int s = 0;
        #pragma unroll
        for (int j = 0; j < 8; ++j) { loc[j] = s; s += cnt[base + j]; }
        const int own = s;
        #pragma unroll
        for (int off = 1; off < 64; off <<= 1) {
            const int n = __shfl_up(s, off, 64);
            if (t >= off) s += n;
        }
        const int excl = s - own;            // exclusive prefix of this lane
        #pragma unroll
        for (int j = 0; j < 8; ++j) {
            const int v = excl + loc[j];
            cur[base + j] = v;
            if (base + j <= NBIN) tile_off[base + j] = v;  // 0..500
        }
    }
    __syncthreads();

    #pragma unroll
    for (int j = 0; j < 8; ++j) {
        const int tok = toks[j];
        const int slot = atomicAdd(&cur[tok >> 6], 1);
        sorted[slot] = make_int2(tok, t * 8 + j);
    }
}

// ---- pass 2: coalesced W sweep, transposed-LDS gather, float4 epilogue ----
__global__ __launch_bounds__(256, 8) void gather_k(const int2* __restrict__ sorted,
                                                   const int* __restrict__ tile_off,
                                                   const float* __restrict__ W,
                                                   const float* __restrict__ bias,
                                                   const float* __restrict__ pe,
                                                   float* __restrict__ out) {
    __shared__ float lds[VT][LROW];          // 64 x 68 x 4B = 17.4 KB -> 8 blk/CU

    const int bid = blockIdx.x;
    const int vt = bid >> 4;                 // 0..499
    const int dt = bid & (NDT - 1);          // 0..15
    const int v0 = vt * VT;
    const int d0 = dt * DT;
    const int t  = threadIdx.x;

    // stage W[d0:d0+64][v0:v0+64] -> transposed lds[v][d], coalesced f4 reads
    {
        const int c4 = t & 15;               // float4 column (v) 0..15
        const int r0 = t >> 4;               // row (d) 0..15
        #pragma unroll
        for (int i = 0; i < 4; ++i) {
            const int row = r0 + i * 16;
            const float4 w4 = *reinterpret_cast<const float4*>(
                W + (size_t)(d0 + row) * VOCAB + v0 + c4 * 4);
            lds[c4 * 4 + 0][row] = w4.x;
            lds[c4 * 4 + 1][row] = w4.y;
            lds[c4 * 4 + 2][row] = w4.z;
            lds[c4 * 4 + 3][row] = w4.w;
        }
    }
    __syncthreads();

    const int a0 = tile_off[vt];
    const int a1 = tile_off[vt + 1];
    const int lane = t & 63;
    const int wv   = t >> 6;                 // wave 0..3
    const int grp  = lane >> 4;              // token group 0..3 within wave
    const int ld   = lane & 15;              // d-float4 index 0..15
    const int d    = d0 + ld * 4;
    const float4 b4 = *reinterpret_cast<const float4*>(bias + d);

    // 16 tokens in flight per wave-quad; per token: 1 b128 LDS read,
    // 1 dwordx4 pe load, 1 dwordx4 out store (256B contiguous per 16 lanes)
    for (int i = a0 + wv * 4 + grp; i < a1; i += 16) {
        const int2 p = sorted[i];
        const int tokl = p.x - v0;
        const int bs   = p.y;
        const int s    = bs & (S_LEN - 1);
        const float4 w4 = *reinterpret_cast<const float4*>(&lds[tokl][ld * 4]);
        const float4 p4 = *reinterpret_cast<const float4*>(pe + (size_t)s * DMODEL + d);
        float4 o;
        o.x = w4.x + b4.x + p4.x;
        o.y = w4.y + b4.y + p4.y;
        o.z = w4.z + b4.z + p4.z;
        o.w = w4.w + b4.w + p4.w;
        *reinterpret_cast<float4*>(out + (size_t)bs * DMODEL + d) = o;
    }
}

// ---- fallback (ws too small): direct gather ----
__global__ __launch_bounds__(256) void embed_pe_direct(const int* __restrict__ text,
                                                       const float* __restrict__ W,
                                                       const float* __restrict__ bias,
                                                       const float* __restrict__ pe,
                                                       float* __restrict__ out) {
    const int bs = blockIdx.x;
    const int s  = bs & (S_LEN - 1);
    const int tok = text[bs];
    const int d = threadIdx.x << 2;
    const float4 b4 = *reinterpret_cast<const float4*>(bias + d);
    const float4 p4 = *reinterpret_cast<const float4*>(pe + (size_t)s * DMODEL + d);
    const float* wcol = W + (size_t)d * VOCAB + tok;
    float4 o;
    o.x = wcol[0]                 + b4.x + p4.x;
    o.y = wcol[(size_t)VOCAB]     + b4.y + p4.y;
    o.z = wcol[(size_t)2 * VOCAB] + b4.z + p4.z;
    o.w = wcol[(size_t)3 * VOCAB] + b4.w + p4.w;
    *reinterpret_cast<float4*>(out + (size_t)bs * DMODEL + d) = o;
}

extern "C" void kernel_launch(void* const* d_in, const int* in_sizes, int n_in,
                              void* d_out, int out_size, void* d_ws, size_t ws_size,
                              hipStream_t stream) {
    const int*   text = (const int*)d_in[0];
    const float* W    = (const float*)d_in[1];
    const float* bias = (const float*)d_in[2];
    const float* pe   = (const float*)d_in[3];
    float*       out  = (float*)d_out;

    const size_t sorted_bytes = (size_t)NTOK * sizeof(int2);   // 64 KB
    const size_t off_bytes    = (NBIN + 1) * sizeof(int);
    if (ws_size < sorted_bytes + off_bytes) {
        embed_pe_direct<<<NTOK, 256, 0, stream>>>(text, W, bias, pe, out);
        return;
    }

    int2* sorted   = (int2*)d_ws;
    int*  tile_off = (int*)((char*)d_ws + sorted_bytes);

    bin_k   <<<1, 1024, 0, stream>>>(text, sorted, tile_off);
    gather_k<<<NBLK, 256, 0, stream>>>(sorted, tile_off, W, bias, pe, out);
}